// Round 9
// baseline (196.457 us; speedup 1.0000x reference)
//
#include <hip/hip_runtime.h>
#include <hip/hip_bf16.h>

#define T_TOK 16384
#define D_DIM 2048
#define E_EXP 64
#define TAU   2e-3f

typedef __bf16 bf16x8 __attribute__((ext_vector_type(8)));
typedef float  f32x16 __attribute__((ext_vector_type(16)));
typedef unsigned short ushort_t;

// workspace layout (bytes)
#define WS_WHI  0                    // ushort[16 chunks][1024 granule-slots][8] = 256KB
#define WS_WLO  (256*1024)
#define WS_PART (512*1024)           // float[512][64] per-block expert prob sums = 128KB
#define WS_FLAG (640*1024)           // int[T] near-tie flags = 64KB

__device__ __forceinline__ unsigned short bf16_rne(float x){
  unsigned int u = __float_as_uint(x);
  return (unsigned short)((u + 0x7FFFu + ((u >> 16) & 1u)) >> 16);
}

__device__ __forceinline__ void ins3(float& v1, int& i1, float& v2, int& i2,
                                     float& v3, int& i3, float v, int i){
  if (v > v1 || (v == v1 && i < i1)) { v3=v2; i3=i2; v2=v1; i2=i1; v1=v; i1=i; }
  else if (v > v2 || (v == v2 && i < i2)) { v3=v2; i3=i2; v2=v; i2=i; }
  else if (v > v3 || (v == v3 && i < i3)) { v3=v; i3=i; }
}

__device__ __forceinline__ void gload16(const void* g, const void* l){
  __builtin_amdgcn_global_load_lds(
      (const __attribute__((address_space(1))) unsigned int*)g,
      (__attribute__((address_space(3))) unsigned int*)l, 16, 0, 0);
}

// Fragment-pack W hi/lo bf16 (same layout as R5).
__global__ void wsplit_kernel(const float* __restrict__ W,
                              ushort_t* __restrict__ whi, ushort_t* __restrict__ wlo){
  const int n = blockIdx.x * 256 + threadIdx.x;   // 64 blocks -> 16384 granules
  const int lane = n & 63;
  const int eh   = (n >> 6) & 1;
  const int w    = (n >> 7) & 7;
  const int c    = n >> 10;
  const float* src = W + (size_t)(eh*32 + (lane & 31))*D_DIM
                       + c*128 + w*16 + (lane >> 5)*8;
  float4 w0 = *reinterpret_cast<const float4*>(src);
  float4 w1 = *reinterpret_cast<const float4*>(src + 4);
  float f[8] = {w0.x,w0.y,w0.z,w0.w,w1.x,w1.y,w1.z,w1.w};
  unsigned h[8], lo[8];
  #pragma unroll
  for (int i = 0; i < 8; ++i){
    h[i]  = bf16_rne(f[i]);
    lo[i] = bf16_rne(f[i] - __uint_as_float(h[i] << 16));
  }
  uint4 hv = { h[0]|(h[1]<<16),  h[2]|(h[3]<<16),  h[4]|(h[5]<<16),  h[6]|(h[7]<<16) };
  uint4 lv = { lo[0]|(lo[1]<<16), lo[2]|(lo[3]<<16), lo[4]|(lo[5]<<16), lo[6]|(lo[7]<<16) };
  *reinterpret_cast<uint4*>(whi + (size_t)n*8) = hv;
  *reinterpret_cast<uint4*>(wlo + (size_t)n*8) = lv;
}

// Main fused kernel — R5 mainloop verbatim (empirical best, 74.8us).
// Tile 32 rows x 64 experts, BK=128 -> 16 chunks, grid 512, 8 waves = (eh, ks).
// X: LDS 2x16KB dbuf via global_load_lds, involutive granule swizzle.
// W: global->VGPR, named dbuf reg sets. Counted vmcnt(6).
// Bookkeeping: non-atomic PART[block][64] + FLAG[row] (no init required).
__launch_bounds__(512, 4)
__global__ void moe_main(const float* __restrict__ X, const float* __restrict__ NZ,
                         const ushort_t* __restrict__ WHI, const ushort_t* __restrict__ WLO,
                         const float* __restrict__ NW, float* __restrict__ OUT,
                         float* __restrict__ PART, int* __restrict__ FLAG)
{
  __shared__ __align__(16) char smem[32768];

  const int tid  = threadIdx.x;
  const int lane = tid & 63;
  const int wv   = tid >> 6;   // 0..7
  const int eh   = wv & 1;     // expert half
  const int ks   = wv >> 1;    // K quarter of each chunk
  const int r0   = blockIdx.x << 5;
  const int m    = lane & 31;
  const int kg   = lane >> 5;

  // --- X staging addresses (per-lane source, wave-uniform LDS dst) ---
  const int n0   = wv*64 + lane;           // granule slot, issue 0 (rows 0..15)
  const int row0 = n0 >> 5, g0 = n0 & 31;
  const int gs0  = (g0 & 24) | ((g0 ^ row0) & 7);
  const char* px0 = (const char*)X + ((size_t)(r0 + row0)*D_DIM + gs0*4) * 4;
  const char* px1 = px0 + (size_t)16*D_DIM*4;   // rows 16..31, same swizzle
  const char* ldsx0 = smem +        wv*1024;    // wave-uniform
  const char* ldsx1 = smem + 8192 + wv*1024;

  // --- W fragment pointers (lane-consecutive 16B granules) ---
  const char* pwh = (const char*)WHI + (size_t)(ks*256 + eh*64 + lane)*16;
  const char* pwl = (const char*)WLO + (size_t)(ks*256 + eh*64 + lane)*16;

  // --- fragment-read LDS byte offsets (chunk-invariant) ---
  const int gf0 = ks*8 + kg*2;     // ks2=0 granule pair
  const int gf1 = gf0 + 4;         // ks2=1
  const int offA0 = m*512 + (((gf0  ) & 24) | (((gf0  ) ^ m) & 7))*16;
  const int offB0 = m*512 + (((gf0+1) & 24) | (((gf0+1) ^ m) & 7))*16;
  const int offA1 = m*512 + (((gf1  ) & 24) | (((gf1  ) ^ m) & 7))*16;
  const int offB1 = m*512 + (((gf1+1) & 24) | (((gf1+1) ^ m) & 7))*16;

  f32x16 acc;
  #pragma unroll
  for (int i = 0; i < 16; ++i) acc[i] = 0.0f;

  uint4 whA0, wlA0, whA1, wlA1;   // W reg set A (even chunks)
  uint4 whB0, wlB0, whB1, wlB1;   // W reg set B (odd chunks)

  #define LOADW(c, H0, L0, H1, L1) do{                                         \
    H0 = *reinterpret_cast<const uint4*>(pwh + (size_t)(c)*16384);             \
    L0 = *reinterpret_cast<const uint4*>(pwl + (size_t)(c)*16384);             \
    H1 = *reinterpret_cast<const uint4*>(pwh + (size_t)(c)*16384 + 2048);      \
    L1 = *reinterpret_cast<const uint4*>(pwl + (size_t)(c)*16384 + 2048);      \
  }while(0)

  #define ISSUE(c, BUF, H0, L0, H1, L1) do{                                    \
    __builtin_amdgcn_sched_barrier(0);                                         \
    gload16(px0 + (size_t)(c)*512, ldsx0 + (BUF));                             \
    gload16(px1 + (size_t)(c)*512, ldsx1 + (BUF));                             \
    LOADW(c, H0, L0, H1, L1);                                                  \
    __builtin_amdgcn_sched_barrier(0);                                         \
  }while(0)

  #define CVT8(fa, fb, ah, al) do{                                             \
    float fv[8] = {fa.x,fa.y,fa.z,fa.w,fb.x,fb.y,fb.z,fb.w};                   \
    _Pragma("unroll")                                                          \
    for (int ii = 0; ii < 8; ++ii){                                            \
      __bf16 hh = (__bf16)fv[ii];                                              \
      ah[ii] = hh; al[ii] = (__bf16)(fv[ii] - (float)hh);                      \
    }                                                                          \
  }while(0)

  #define KS2(BUF, OA, OB, WH, WL) do{                                         \
    float4 fa = *reinterpret_cast<const float4*>(smem + (BUF) + (OA));         \
    float4 fb = *reinterpret_cast<const float4*>(smem + (BUF) + (OB));         \
    bf16x8 ah, al;                                                             \
    CVT8(fa, fb, ah, al);                                                      \
    bf16x8 bh = __builtin_bit_cast(bf16x8, WH);                                \
    bf16x8 bl = __builtin_bit_cast(bf16x8, WL);                                \
    acc = __builtin_amdgcn_mfma_f32_32x32x16_bf16(ah, bh, acc, 0, 0, 0);       \
    acc = __builtin_amdgcn_mfma_f32_32x32x16_bf16(ah, bl, acc, 0, 0, 0);       \
    acc = __builtin_amdgcn_mfma_f32_32x32x16_bf16(al, bh, acc, 0, 0, 0);       \
  }while(0)

  #define PHASE(cc, H0, L0, H1, L1, BUF, WNTOK, DOISS) do{                     \
    asm volatile("s_waitcnt vmcnt(" WNTOK ")" ::: "memory");                   \
    __builtin_amdgcn_sched_barrier(0);                                         \
    __builtin_amdgcn_s_barrier();                                              \
    KS2(BUF, offA0, offB0, H0, L0);                                            \
    KS2(BUF, offA1, offB1, H1, L1);                                            \
    __builtin_amdgcn_s_barrier();                                              \
    if (DOISS) ISSUE((cc) + 2, BUF, H0, L0, H1, L1);                           \
  }while(0)

  // prologue: clumps 0 (set A, buf0) and 1 (set B, buf1)
  ISSUE(0, 0,     whA0, wlA0, whA1, wlA1);
  ISSUE(1, 16384, whB0, wlB0, whB1, wlB1);

  #pragma unroll 1
  for (int g = 0; g < 7; ++g){
    PHASE(2*g,     whA0, wlA0, whA1, wlA1, 0,     "6", 1);
    PHASE(2*g + 1, whB0, wlB0, whB1, wlB1, 16384, "6", 1);
  }
  PHASE(14, whA0, wlA0, whA1, wlA1, 0,     "6", 0);
  PHASE(15, whB0, wlB0, whB1, wlB1, 16384, "0", 0);

  #undef PHASE
  #undef KS2
  #undef CVT8
  #undef ISSUE
  #undef LOADW

  // ---- epilogue: K-quarter reduction (deterministic 4-phase chain) ----
  float* lgts = (float*)(smem);            // [32][64]  (buf0, consumed)
  float* nzs  = (float*)(smem + 8192);     // [32][64]
  float* prb  = (float*)(smem + 16384);    // [32][64]  (buf1, consumed)
  float* nws  = (float*)(smem + 24576);    // [64]
  const int ex = eh*32 + m;

  __syncthreads();
  if (ks == 0){
    #pragma unroll
    for (int r = 0; r < 16; ++r){
      int rr = (r & 3) + ((r >> 2) << 3) + (kg << 2);   // verified 32x32 C/D layout
      lgts[rr*64 + ex] = acc[r];
    }
  }
  __syncthreads();
  #pragma unroll
  for (int p = 1; p < 4; ++p){
    if (ks == p){
      #pragma unroll
      for (int r = 0; r < 16; ++r){
        int rr = (r & 3) + ((r >> 2) << 3) + (kg << 2);
        lgts[rr*64 + ex] += acc[r];
      }
    }
    __syncthreads();
  }

  // stage noise + noise_weight
  const int sr = tid >> 4, sc = tid & 15;
  *reinterpret_cast<float4*>(&nzs[sr*64 + sc*4]) =
    *reinterpret_cast<const float4*>(NZ + (size_t)(r0 + sr)*E_EXP + sc*4);
  if (tid < 64) nws[tid] = NW[tid];
  __syncthreads();

  // gating: waves 0..3, 8 lanes per row, 8 experts per lane
  if (wv < 4){
    const int rrow = (wv << 3) + (lane >> 3);
    const int j    = lane & 7;
    const int trow = r0 + rrow;
    float cl[8];
    float v1 = -INFINITY, v2 = -INFINITY, v3 = -INFINITY;
    int   i1 = 1 << 29,   i2 = 1 << 29,   i3 = 1 << 29;
    #pragma unroll
    for (int mm = 0; mm < 8; ++mm){
      int q = j + (mm << 3);
      float lg = lgts[rrow*64 + q];
      cl[mm] = lg;
      float vn = fmaf(nzs[rrow*64 + q], nws[q], lg);   // NOISY_STD = 1
      ins3(v1,i1,v2,i2,v3,i3, vn, q);
    }
    #pragma unroll
    for (int d = 1; d < 8; d <<= 1){
      float ov1 = __shfl_xor(v1, d, 8), ov2 = __shfl_xor(v2, d, 8), ov3 = __shfl_xor(v3, d, 8);
      int   oi1 = __shfl_xor(i1, d, 8), oi2 = __shfl_xor(i2, d, 8), oi3 = __shfl_xor(i3, d, 8);
      ins3(v1,i1,v2,i2,v3,i3, ov1, oi1);
      ins3(v1,i1,v2,i2,v3,i3, ov2, oi2);
      ins3(v1,i1,v2,i2,v3,i3, ov3, oi3);
    }
    float e1 = expf(v2 - v1);
    float g0g = 1.0f / (1.0f + e1);
    float g1g = e1 * g0g;

    float mx = cl[0];
    #pragma unroll
    for (int mm = 1; mm < 8; ++mm) mx = fmaxf(mx, cl[mm]);
    #pragma unroll
    for (int d = 1; d < 8; d <<= 1) mx = fmaxf(mx, __shfl_xor(mx, d, 8));
    float sum = 0.0f, exv[8];
    #pragma unroll
    for (int mm = 0; mm < 8; ++mm){ exv[mm] = expf(cl[mm] - mx); sum += exv[mm]; }
    #pragma unroll
    for (int d = 1; d < 8; d <<= 1) sum += __shfl_xor(sum, d, 8);
    float inv = 1.0f / sum;
    #pragma unroll
    for (int mm = 0; mm < 8; ++mm) prb[rrow*64 + j + (mm << 3)] = exv[mm] * inv;

    if (j == 0){
      OUT[(size_t)T_TOK*E_EXP + (size_t)trow*2]     = (float)i1;
      OUT[(size_t)T_TOK*E_EXP + (size_t)trow*2 + 1] = (float)i2;
      FLAG[trow] = ((v1 - v2 < TAU) || (v2 - v3 < TAU)) ? 1 : 0;  // near-tie flag
    }
    #pragma unroll
    for (int mm = 0; mm < 8; ++mm){
      int q = j + (mm << 3);
      lgts[rrow*64 + q] = (q == i1) ? g0g : ((q == i2) ? g1g : 0.0f);
    }
  }
  __syncthreads();

  // coalesced gates write (512 threads x float4)
  *reinterpret_cast<float4*>(OUT + (size_t)(r0 + sr)*E_EXP + sc*4) =
    *reinterpret_cast<const float4*>(&lgts[sr*64 + sc*4]);
  // per-expert prob column sums -> non-atomic per-block partial
  if (tid < 64){
    float s0 = 0.0f;
    #pragma unroll 8
    for (int rr2 = 0; rr2 < 32; ++rr2) s0 += prb[rr2*64 + tid];
    PART[(size_t)blockIdx.x*64 + tid] = s0;
  }
}

// Merged finalize: block 0 computes the load-balance loss from PART;
// blocks 1..512 scan their 32 rows' flags and fp64-recompute flagged rows.
__launch_bounds__(256)
__global__ void moe_finalize(const float* __restrict__ X, const float* __restrict__ NZ,
                             const float* __restrict__ WG, const float* __restrict__ NW,
                             float* __restrict__ OUT, const float* __restrict__ PART,
                             const int* __restrict__ FLAG)
{
  __shared__ __align__(16) float xl[2048];
  __shared__ double lz[64];
  __shared__ double ps[4][64];
  __shared__ int   si1, si2;
  __shared__ float sg0, sg1;

  if (blockIdx.x == 0){
    const int e = threadIdx.x & 63;
    const int p = threadIdx.x >> 6;   // 0..3
    double s = 0.0;
    for (int b = p; b < 512; b += 4) s += (double)PART[(size_t)b*64 + e];
    ps[p][e] = s;
    __syncthreads();
    if (threadIdx.x < 64){
      double tot = ps[0][e] + ps[1][e] + ps[2][e] + ps[3][e];
      double d = tot * (1.0 / T_TOK) - (1.0 / 64.0);
      double sq = d * d;
      #pragma unroll
      for (int off = 1; off < 64; off <<= 1) sq += __shfl_xor(sq, off, 64);
      if (e == 0) OUT[(size_t)T_TOK*E_EXP + T_TOK*2] = (float)(sq * (0.01 / 64.0));
    }
    return;
  }

  const int r0   = (blockIdx.x - 1) * 32;
  const int lane = threadIdx.x & 63;
  const int wv   = threadIdx.x >> 6;
  for (int i = 0; i < 32; ++i){
    const int t = r0 + i;
    if (FLAG[t] == 0) continue;       // uniform across block
    {
      int off = threadIdx.x * 8;
      *reinterpret_cast<float4*>(xl + off) =
        *reinterpret_cast<const float4*>(X + (size_t)t*D_DIM + off);
      *reinterpret_cast<float4*>(xl + off + 4) =
        *reinterpret_cast<const float4*>(X + (size_t)t*D_DIM + off + 4);
    }
    __syncthreads();
    for (int s = 0; s < 16; ++s){
      const int e = wv*16 + s;
      const float* wr = WG + (size_t)e*D_DIM;
      double acc = 0.0;
      #pragma unroll
      for (int it = 0; it < 8; ++it){
        float4 w4 = *reinterpret_cast<const float4*>(wr + it*256 + lane*4);
        float4 x4 = *reinterpret_cast<const float4*>(xl + it*256 + lane*4);
        acc += (double)x4.x * (double)w4.x;
        acc += (double)x4.y * (double)w4.y;
        acc += (double)x4.z * (double)w4.z;
        acc += (double)x4.w * (double)w4.w;
      }
      #pragma unroll
      for (int off = 1; off < 64; off <<= 1) acc += __shfl_xor(acc, off, 64);
      if (lane == 0)
        lz[e] = acc + (double)NZ[(size_t)t*E_EXP + e] * (double)NW[e];
    }
    __syncthreads();
    if (threadIdx.x == 0){
      double b1 = -1e300, b2 = -1e300; int j1 = 0, j2 = 0;
      for (int q = 0; q < 64; ++q){
        double v = lz[q];
        if (v > b1){ b2 = b1; j2 = j1; b1 = v; j1 = q; }
        else if (v > b2){ b2 = v; j2 = q; }
      }
      double ee = exp(b2 - b1);
      sg0 = (float)(1.0 / (1.0 + ee));
      sg1 = (float)(ee / (1.0 + ee));
      si1 = j1; si2 = j2;
      OUT[(size_t)T_TOK*E_EXP + (size_t)t*2]     = (float)j1;
      OUT[(size_t)T_TOK*E_EXP + (size_t)t*2 + 1] = (float)j2;
    }
    __syncthreads();
    if (threadIdx.x < 64)
      OUT[(size_t)t*E_EXP + threadIdx.x] = (threadIdx.x == si1) ? sg0 :
                                           ((threadIdx.x == si2) ? sg1 : 0.0f);
    __syncthreads();
  }
}

extern "C" void kernel_launch(void* const* d_in, const int* in_sizes, int n_in,
                              void* d_out, int out_size, void* d_ws, size_t ws_size,
                              hipStream_t stream)
{
  const float* X  = (const float*)d_in[0];
  const float* NZ = (const float*)d_in[1];
  const float* WG = (const float*)d_in[2];
  const float* NW = (const float*)d_in[3];
  float* OUT = (float*)d_out;
  char*  ws  = (char*)d_ws;
  ushort_t* WHI = (ushort_t*)(ws + WS_WHI);
  ushort_t* WLO = (ushort_t*)(ws + WS_WLO);
  float* PART = (float*)(ws + WS_PART);
  int*   FLAG = (int*)(ws + WS_FLAG);

  wsplit_kernel<<<dim3(64), dim3(256), 0, stream>>>(WG, WHI, WLO);
  moe_main<<<dim3(T_TOK/32), dim3(512), 0, stream>>>(X, NZ, WHI, WLO, NW, OUT, PART, FLAG);
  moe_finalize<<<dim3(513), dim3(256), 0, stream>>>(X, NZ, WG, NW, OUT, PART, FLAG);
}

// Round 10
// 111.730 us; speedup vs baseline: 1.7583x; 1.7583x over previous
//
#include <hip/hip_runtime.h>
#include <hip/hip_bf16.h>

#define T_TOK 16384
#define D_DIM 2048
#define E_EXP 64
#define TAU   2e-3f

typedef __bf16 bf16x8 __attribute__((ext_vector_type(8)));
typedef float  f32x16 __attribute__((ext_vector_type(16)));
typedef unsigned short ushort_t;

// workspace layout (bytes)
#define WS_WHI  0                    // ushort[16 chunks][1024 granule-slots][8] = 256KB
#define WS_WLO  (256*1024)
#define WS_SUM  (512*1024)           // double[64] expert prob sums
#define WS_CNT  (512*1024 + 512)     // int flag count
#define WS_FLG  (512*1024 + 1024)    // int[T] flagged rows

__device__ __forceinline__ unsigned short bf16_rne(float x){
  unsigned int u = __float_as_uint(x);
  return (unsigned short)((u + 0x7FFFu + ((u >> 16) & 1u)) >> 16);
}

__device__ __forceinline__ void ins3(float& v1, int& i1, float& v2, int& i2,
                                     float& v3, int& i3, float v, int i){
  if (v > v1 || (v == v1 && i < i1)) { v3=v2; i3=i2; v2=v1; i2=i1; v1=v; i1=i; }
  else if (v > v2 || (v == v2 && i < i2)) { v3=v2; i3=i2; v2=v; i2=i; }
  else if (v > v3 || (v == v3 && i < i3)) { v3=v; i3=i; }
}

__device__ __forceinline__ void gload16(const void* g, const void* l){
  __builtin_amdgcn_global_load_lds(
      (const __attribute__((address_space(1))) unsigned int*)g,
      (__attribute__((address_space(3))) unsigned int*)l, 16, 0, 0);
}

// Fragment-pack W hi/lo bf16 (R5 layout) + init ESUM/FCNT (no memset dispatch).
__global__ void wsplit_kernel(const float* __restrict__ W,
                              ushort_t* __restrict__ whi, ushort_t* __restrict__ wlo,
                              double* __restrict__ ESUM, int* __restrict__ FCNT){
  const int n = blockIdx.x * 256 + threadIdx.x;   // 64 blocks -> 16384 granules
  if (blockIdx.x == 0){
    if (threadIdx.x < 64) ESUM[threadIdx.x] = 0.0;
    else if (threadIdx.x == 64) *FCNT = 0;
  }
  const int lane = n & 63;
  const int eh   = (n >> 6) & 1;
  const int w    = (n >> 7) & 7;
  const int c    = n >> 10;
  const float* src = W + (size_t)(eh*32 + (lane & 31))*D_DIM
                       + c*128 + w*16 + (lane >> 5)*8;
  float4 w0 = *reinterpret_cast<const float4*>(src);
  float4 w1 = *reinterpret_cast<const float4*>(src + 4);
  float f[8] = {w0.x,w0.y,w0.z,w0.w,w1.x,w1.y,w1.z,w1.w};
  unsigned h[8], lo[8];
  #pragma unroll
  for (int i = 0; i < 8; ++i){
    h[i]  = bf16_rne(f[i]);
    lo[i] = bf16_rne(f[i] - __uint_as_float(h[i] << 16));
  }
  uint4 hv = { h[0]|(h[1]<<16),  h[2]|(h[3]<<16),  h[4]|(h[5]<<16),  h[6]|(h[7]<<16) };
  uint4 lv = { lo[0]|(lo[1]<<16), lo[2]|(lo[3]<<16), lo[4]|(lo[5]<<16), lo[6]|(lo[7]<<16) };
  *reinterpret_cast<uint4*>(whi + (size_t)n*8) = hv;
  *reinterpret_cast<uint4*>(wlo + (size_t)n*8) = lv;
}

// Main fused kernel — R5 mainloop verbatim (empirical best, 74.8us).
// Tile 32 rows x 64 experts, BK=128 -> 16 chunks, grid 512, 8 waves = (eh, ks).
// X: LDS 2x16KB dbuf via global_load_lds, involutive granule swizzle.
// W: global->VGPR, named dbuf reg sets. Counted vmcnt(6).
__launch_bounds__(512, 4)
__global__ void moe_main(const float* __restrict__ X, const float* __restrict__ NZ,
                         const ushort_t* __restrict__ WHI, const ushort_t* __restrict__ WLO,
                         const float* __restrict__ NW, float* __restrict__ OUT,
                         double* __restrict__ ESUM, int* __restrict__ FCNT,
                         int* __restrict__ FLIST)
{
  __shared__ __align__(16) char smem[32768];

  const int tid  = threadIdx.x;
  const int lane = tid & 63;
  const int wv   = tid >> 6;   // 0..7
  const int eh   = wv & 1;     // expert half
  const int ks   = wv >> 1;    // K quarter of each chunk
  const int r0   = blockIdx.x << 5;
  const int m    = lane & 31;
  const int kg   = lane >> 5;

  // --- X staging addresses (per-lane source, wave-uniform LDS dst) ---
  const int n0   = wv*64 + lane;           // granule slot, issue 0 (rows 0..15)
  const int row0 = n0 >> 5, g0 = n0 & 31;
  const int gs0  = (g0 & 24) | ((g0 ^ row0) & 7);
  const char* px0 = (const char*)X + ((size_t)(r0 + row0)*D_DIM + gs0*4) * 4;
  const char* px1 = px0 + (size_t)16*D_DIM*4;   // rows 16..31, same swizzle
  const char* ldsx0 = smem +        wv*1024;    // wave-uniform
  const char* ldsx1 = smem + 8192 + wv*1024;

  // --- W fragment pointers (lane-consecutive 16B granules) ---
  const char* pwh = (const char*)WHI + (size_t)(ks*256 + eh*64 + lane)*16;
  const char* pwl = (const char*)WLO + (size_t)(ks*256 + eh*64 + lane)*16;

  // --- fragment-read LDS byte offsets (chunk-invariant) ---
  const int gf0 = ks*8 + kg*2;     // ks2=0 granule pair
  const int gf1 = gf0 + 4;         // ks2=1
  const int offA0 = m*512 + (((gf0  ) & 24) | (((gf0  ) ^ m) & 7))*16;
  const int offB0 = m*512 + (((gf0+1) & 24) | (((gf0+1) ^ m) & 7))*16;
  const int offA1 = m*512 + (((gf1  ) & 24) | (((gf1  ) ^ m) & 7))*16;
  const int offB1 = m*512 + (((gf1+1) & 24) | (((gf1+1) ^ m) & 7))*16;

  f32x16 acc;
  #pragma unroll
  for (int i = 0; i < 16; ++i) acc[i] = 0.0f;

  uint4 whA0, wlA0, whA1, wlA1;   // W reg set A (even chunks)
  uint4 whB0, wlB0, whB1, wlB1;   // W reg set B (odd chunks)

  #define LOADW(c, H0, L0, H1, L1) do{                                         \
    H0 = *reinterpret_cast<const uint4*>(pwh + (size_t)(c)*16384);             \
    L0 = *reinterpret_cast<const uint4*>(pwl + (size_t)(c)*16384);             \
    H1 = *reinterpret_cast<const uint4*>(pwh + (size_t)(c)*16384 + 2048);      \
    L1 = *reinterpret_cast<const uint4*>(pwl + (size_t)(c)*16384 + 2048);      \
  }while(0)

  #define ISSUE(c, BUF, H0, L0, H1, L1) do{                                    \
    __builtin_amdgcn_sched_barrier(0);                                         \
    gload16(px0 + (size_t)(c)*512, ldsx0 + (BUF));                             \
    gload16(px1 + (size_t)(c)*512, ldsx1 + (BUF));                             \
    LOADW(c, H0, L0, H1, L1);                                                  \
    __builtin_amdgcn_sched_barrier(0);                                         \
  }while(0)

  #define CVT8(fa, fb, ah, al) do{                                             \
    float fv[8] = {fa.x,fa.y,fa.z,fa.w,fb.x,fb.y,fb.z,fb.w};                   \
    _Pragma("unroll")                                                          \
    for (int ii = 0; ii < 8; ++ii){                                            \
      __bf16 hh = (__bf16)fv[ii];                                              \
      ah[ii] = hh; al[ii] = (__bf16)(fv[ii] - (float)hh);                      \
    }                                                                          \
  }while(0)

  #define KS2(BUF, OA, OB, WH, WL) do{                                         \
    float4 fa = *reinterpret_cast<const float4*>(smem + (BUF) + (OA));         \
    float4 fb = *reinterpret_cast<const float4*>(smem + (BUF) + (OB));         \
    bf16x8 ah, al;                                                             \
    CVT8(fa, fb, ah, al);                                                      \
    bf16x8 bh = __builtin_bit_cast(bf16x8, WH);                                \
    bf16x8 bl = __builtin_bit_cast(bf16x8, WL);                                \
    acc = __builtin_amdgcn_mfma_f32_32x32x16_bf16(ah, bh, acc, 0, 0, 0);       \
    acc = __builtin_amdgcn_mfma_f32_32x32x16_bf16(ah, bl, acc, 0, 0, 0);       \
    acc = __builtin_amdgcn_mfma_f32_32x32x16_bf16(al, bh, acc, 0, 0, 0);       \
  }while(0)

  #define PHASE(cc, H0, L0, H1, L1, BUF, WNTOK, DOISS) do{                     \
    asm volatile("s_waitcnt vmcnt(" WNTOK ")" ::: "memory");                   \
    __builtin_amdgcn_sched_barrier(0);                                         \
    __builtin_amdgcn_s_barrier();                                              \
    KS2(BUF, offA0, offB0, H0, L0);                                            \
    KS2(BUF, offA1, offB1, H1, L1);                                            \
    __builtin_amdgcn_s_barrier();                                              \
    if (DOISS) ISSUE((cc) + 2, BUF, H0, L0, H1, L1);                           \
  }while(0)

  // prologue: clumps 0 (set A, buf0) and 1 (set B, buf1)
  ISSUE(0, 0,     whA0, wlA0, whA1, wlA1);
  ISSUE(1, 16384, whB0, wlB0, whB1, wlB1);

  #pragma unroll 1
  for (int g = 0; g < 7; ++g){
    PHASE(2*g,     whA0, wlA0, whA1, wlA1, 0,     "6", 1);
    PHASE(2*g + 1, whB0, wlB0, whB1, wlB1, 16384, "6", 1);
  }
  PHASE(14, whA0, wlA0, whA1, wlA1, 0,     "6", 0);
  PHASE(15, whB0, wlB0, whB1, wlB1, 16384, "0", 0);

  #undef PHASE
  #undef KS2
  #undef CVT8
  #undef ISSUE
  #undef LOADW

  // ---- epilogue: K-quarter reduction (deterministic 4-phase chain) ----
  float* lgts = (float*)(smem);            // [32][64]  (buf0, consumed)
  float* nzs  = (float*)(smem + 8192);     // [32][64]
  float* prb  = (float*)(smem + 16384);    // [32][64]  (buf1, consumed)
  float* nws  = (float*)(smem + 24576);    // [64]
  const int ex = eh*32 + m;

  __syncthreads();
  if (ks == 0){
    #pragma unroll
    for (int r = 0; r < 16; ++r){
      int rr = (r & 3) + ((r >> 2) << 3) + (kg << 2);   // verified 32x32 C/D layout
      lgts[rr*64 + ex] = acc[r];
    }
  }
  __syncthreads();
  #pragma unroll
  for (int p = 1; p < 4; ++p){
    if (ks == p){
      #pragma unroll
      for (int r = 0; r < 16; ++r){
        int rr = (r & 3) + ((r >> 2) << 3) + (kg << 2);
        lgts[rr*64 + ex] += acc[r];
      }
    }
    __syncthreads();
  }

  // stage noise + noise_weight
  const int sr = tid >> 4, sc = tid & 15;
  *reinterpret_cast<float4*>(&nzs[sr*64 + sc*4]) =
    *reinterpret_cast<const float4*>(NZ + (size_t)(r0 + sr)*E_EXP + sc*4);
  if (tid < 64) nws[tid] = NW[tid];
  __syncthreads();

  // gating: waves 0..3, 8 lanes per row, 8 experts per lane
  if (wv < 4){
    const int rrow = (wv << 3) + (lane >> 3);
    const int j    = lane & 7;
    const int trow = r0 + rrow;
    float cl[8];
    float v1 = -INFINITY, v2 = -INFINITY, v3 = -INFINITY;
    int   i1 = 1 << 29,   i2 = 1 << 29,   i3 = 1 << 29;
    #pragma unroll
    for (int mm = 0; mm < 8; ++mm){
      int q = j + (mm << 3);
      float lg = lgts[rrow*64 + q];
      cl[mm] = lg;
      float vn = fmaf(nzs[rrow*64 + q], nws[q], lg);   // NOISY_STD = 1
      ins3(v1,i1,v2,i2,v3,i3, vn, q);
    }
    #pragma unroll
    for (int d = 1; d < 8; d <<= 1){
      float ov1 = __shfl_xor(v1, d, 8), ov2 = __shfl_xor(v2, d, 8), ov3 = __shfl_xor(v3, d, 8);
      int   oi1 = __shfl_xor(i1, d, 8), oi2 = __shfl_xor(i2, d, 8), oi3 = __shfl_xor(i3, d, 8);
      ins3(v1,i1,v2,i2,v3,i3, ov1, oi1);
      ins3(v1,i1,v2,i2,v3,i3, ov2, oi2);
      ins3(v1,i1,v2,i2,v3,i3, ov3, oi3);
    }
    float e1 = expf(v2 - v1);
    float g0g = 1.0f / (1.0f + e1);
    float g1g = e1 * g0g;

    float mx = cl[0];
    #pragma unroll
    for (int mm = 1; mm < 8; ++mm) mx = fmaxf(mx, cl[mm]);
    #pragma unroll
    for (int d = 1; d < 8; d <<= 1) mx = fmaxf(mx, __shfl_xor(mx, d, 8));
    float sum = 0.0f, exv[8];
    #pragma unroll
    for (int mm = 0; mm < 8; ++mm){ exv[mm] = expf(cl[mm] - mx); sum += exv[mm]; }
    #pragma unroll
    for (int d = 1; d < 8; d <<= 1) sum += __shfl_xor(sum, d, 8);
    float inv = 1.0f / sum;
    #pragma unroll
    for (int mm = 0; mm < 8; ++mm) prb[rrow*64 + j + (mm << 3)] = exv[mm] * inv;

    if (j == 0){
      OUT[(size_t)T_TOK*E_EXP + (size_t)trow*2]     = (float)i1;
      OUT[(size_t)T_TOK*E_EXP + (size_t)trow*2 + 1] = (float)i2;
      if ((v1 - v2 < TAU) || (v2 - v3 < TAU)){   // near-tie -> fp64 fixup
        int slot = atomicAdd(FCNT, 1);
        FLIST[slot] = trow;
      }
    }
    #pragma unroll
    for (int mm = 0; mm < 8; ++mm){
      int q = j + (mm << 3);
      lgts[rrow*64 + q] = (q == i1) ? g0g : ((q == i2) ? g1g : 0.0f);
    }
  }
  __syncthreads();

  // coalesced gates write (512 threads x float4)
  *reinterpret_cast<float4*>(OUT + (size_t)(r0 + sr)*E_EXP + sc*4) =
    *reinterpret_cast<const float4*>(&lgts[sr*64 + sc*4]);
  // per-expert prob column sums -> one f64 atomic per expert per block
  if (tid < 64){
    float s0 = 0.0f;
    #pragma unroll 8
    for (int rr2 = 0; rr2 < 32; ++rr2) s0 += prb[rr2*64 + tid];
    atomicAdd(&ESUM[tid], (double)s0);
  }
}

// Merged finalize: block 0 = load-balance loss (parallel ESUM reads);
// blocks 1..511 grid-stride the COMPACT near-tie list (fp64 recompute).
__launch_bounds__(256)
__global__ void moe_finalize(const float* __restrict__ X, const float* __restrict__ NZ,
                             const float* __restrict__ WG, const float* __restrict__ NW,
                             float* __restrict__ OUT, const double* __restrict__ ESUM,
                             const int* __restrict__ FCNT, const int* __restrict__ FLIST)
{
  if (blockIdx.x == 0){
    if (threadIdx.x < 64){
      const int e = threadIdx.x;
      double d = ESUM[e] * (1.0 / T_TOK) - (1.0 / 64.0);
      double sq = d * d;
      #pragma unroll
      for (int off = 1; off < 64; off <<= 1) sq += __shfl_xor(sq, off, 64);
      if (e == 0) OUT[(size_t)T_TOK*E_EXP + T_TOK*2] = (float)(sq * (0.01 / 64.0));
    }
    return;
  }

  __shared__ __align__(16) float xl[2048];
  __shared__ double lz[64];
  __shared__ int   si1, si2;
  __shared__ float sg0, sg1;
  const int n    = *FCNT;
  const int lane = threadIdx.x & 63;
  const int wv   = threadIdx.x >> 6;
  for (int idx = blockIdx.x - 1; idx < n; idx += 511){
    const int t = FLIST[idx];
    {
      int off = threadIdx.x * 8;
      *reinterpret_cast<float4*>(xl + off) =
        *reinterpret_cast<const float4*>(X + (size_t)t*D_DIM + off);
      *reinterpret_cast<float4*>(xl + off + 4) =
        *reinterpret_cast<const float4*>(X + (size_t)t*D_DIM + off + 4);
    }
    __syncthreads();
    for (int s = 0; s < 16; ++s){
      const int e = wv*16 + s;
      const float* wr = WG + (size_t)e*D_DIM;
      double acc = 0.0;
      #pragma unroll
      for (int it = 0; it < 8; ++it){
        float4 w4 = *reinterpret_cast<const float4*>(wr + it*256 + lane*4);
        float4 x4 = *reinterpret_cast<const float4*>(xl + it*256 + lane*4);
        acc += (double)x4.x * (double)w4.x;
        acc += (double)x4.y * (double)w4.y;
        acc += (double)x4.z * (double)w4.z;
        acc += (double)x4.w * (double)w4.w;
      }
      #pragma unroll
      for (int off = 1; off < 64; off <<= 1) acc += __shfl_xor(acc, off, 64);
      if (lane == 0)
        lz[e] = acc + (double)NZ[(size_t)t*E_EXP + e] * (double)NW[e];
    }
    __syncthreads();
    if (threadIdx.x == 0){
      double b1 = -1e300, b2 = -1e300; int j1 = 0, j2 = 0;
      for (int q = 0; q < 64; ++q){
        double v = lz[q];
        if (v > b1){ b2 = b1; j2 = j1; b1 = v; j1 = q; }
        else if (v > b2){ b2 = v; j2 = q; }
      }
      double ee = exp(b2 - b1);
      sg0 = (float)(1.0 / (1.0 + ee));
      sg1 = (float)(ee / (1.0 + ee));
      si1 = j1; si2 = j2;
      OUT[(size_t)T_TOK*E_EXP + (size_t)t*2]     = (float)j1;
      OUT[(size_t)T_TOK*E_EXP + (size_t)t*2 + 1] = (float)j2;
    }
    __syncthreads();
    if (threadIdx.x < 64)
      OUT[(size_t)t*E_EXP + threadIdx.x] = (threadIdx.x == si1) ? sg0 :
                                           ((threadIdx.x == si2) ? sg1 : 0.0f);
    __syncthreads();
  }
}

extern "C" void kernel_launch(void* const* d_in, const int* in_sizes, int n_in,
                              void* d_out, int out_size, void* d_ws, size_t ws_size,
                              hipStream_t stream)
{
  const float* X  = (const float*)d_in[0];
  const float* NZ = (const float*)d_in[1];
  const float* WG = (const float*)d_in[2];
  const float* NW = (const float*)d_in[3];
  float* OUT = (float*)d_out;
  char*  ws  = (char*)d_ws;
  ushort_t* WHI = (ushort_t*)(ws + WS_WHI);
  ushort_t* WLO = (ushort_t*)(ws + WS_WLO);
  double* ESUM = (double*)(ws + WS_SUM);
  int* FCNT  = (int*)(ws + WS_CNT);
  int* FLIST = (int*)(ws + WS_FLG);

  wsplit_kernel<<<dim3(64), dim3(256), 0, stream>>>(WG, WHI, WLO, ESUM, FCNT);
  moe_main<<<dim3(T_TOK/32), dim3(512), 0, stream>>>(X, NZ, WHI, WLO, NW, OUT, ESUM, FCNT, FLIST);
  moe_finalize<<<dim3(512), dim3(256), 0, stream>>>(X, NZ, WG, NW, OUT, ESUM, FCNT, FLIST);
}